// Round 7
// baseline (768.346 us; speedup 1.0000x reference)
//
#include <hip/hip_runtime.h>

#define EMBED 32
#define HIDDEN 64
#define NCLS 10

// ============ CSR construction (unchanged, proven) ============

__global__ void deg_kernel(const int* __restrict__ dst, int* __restrict__ deg, int nEdges) {
    int e = blockIdx.x * blockDim.x + threadIdx.x;
    if (e >= nEdges) return;
    atomicAdd(&deg[dst[e]], 1);
}

__global__ void block_sum_kernel(const int* __restrict__ deg, int* __restrict__ blockSums, int n) {
    __shared__ int s[256];
    int i = blockIdx.x * 256 + threadIdx.x;
    s[threadIdx.x] = (i < n) ? deg[i] : 0;
    __syncthreads();
    for (int off = 128; off > 0; off >>= 1) {
        if (threadIdx.x < off) s[threadIdx.x] += s[threadIdx.x + off];
        __syncthreads();
    }
    if (threadIdx.x == 0) blockSums[blockIdx.x] = s[0];
}

__global__ void scan_sums_kernel(int* blockSums, int nb) {
    if (blockIdx.x == 0 && threadIdx.x == 0) {
        int acc = 0;
        for (int i = 0; i < nb; ++i) { int v = blockSums[i]; blockSums[i] = acc; acc += v; }
    }
}

__global__ void scan_local_kernel(const int* __restrict__ deg, const int* __restrict__ blockSums,
                                  int* __restrict__ rowptr, int n) {
    __shared__ int s[256];
    int i = blockIdx.x * 256 + threadIdx.x;
    int v = (i < n) ? deg[i] : 0;
    s[threadIdx.x] = v;
    __syncthreads();
    for (int off = 1; off < 256; off <<= 1) {
        int t = (threadIdx.x >= off) ? s[threadIdx.x - off] : 0;
        __syncthreads();
        s[threadIdx.x] += t;
        __syncthreads();
    }
    if (i < n) rowptr[i] = blockSums[blockIdx.x] + s[threadIdx.x] - v;  // exclusive
}

__global__ void fill_kernel(const int* __restrict__ src, const int* __restrict__ dst,
                            const int* __restrict__ rowptr, int* __restrict__ cursor,
                            int* __restrict__ nbr, int nEdges) {
    int e = blockIdx.x * blockDim.x + threadIdx.x;
    if (e >= nEdges) return;
    int d = dst[e];
    int pos = atomicAdd(&cursor[d], 1);
    nbr[rowptr[d] + pos] = src[e];
}

// ============ SPLIT PATH: low-VGPR gathers + streaming GEMM updates ============

// layer-1 aggregation: agg1[n][f] = mean_j embed[node_ids[nbr_j]][f]   (no LDS, tiny VGPR)
__launch_bounds__(256)
__global__ void gather1_kernel(const int* __restrict__ nbr, const int* __restrict__ rowptr,
                               const int* __restrict__ deg, const int* __restrict__ node_ids,
                               const float* __restrict__ embed, float* __restrict__ agg1,
                               int nNodes) {
    int wave = threadIdx.x >> 6, lane = threadIdx.x & 63;
    int half = lane >> 5, f = lane & 31;
    int wid = blockIdx.x * 4 + wave, stride = gridDim.x * 4;
    for (int n = wid; n < nNodes; n += stride) {
        int dg = deg[n], start = rowptr[n];
        float s0 = 0.f, s1 = 0.f;
        int j = half;
        for (; j + 2 < dg; j += 4) {
            int n0 = nbr[start + j];
            int n1 = nbr[start + j + 2];
            s0 += embed[(size_t)node_ids[n0] * EMBED + f];
            s1 += embed[(size_t)node_ids[n1] * EMBED + f];
        }
        for (; j < dg; j += 2)
            s0 += embed[(size_t)node_ids[nbr[start + j]] * EMBED + f];
        float sum = s0 + s1;
        sum += __shfl_xor(sum, 32);
        if (half == 0) agg1[(size_t)n * EMBED + f] = sum / fmaxf((float)dg, 1.f);
    }
}

// layer-1 update: h1 = relu(agg1@W1l + b1 + x@W1r), 2 nodes/wave, paired-weight b64 reads
__launch_bounds__(512)
__global__ void update1_kernel(const float* __restrict__ agg1, const int* __restrict__ node_ids,
                               const float* __restrict__ embed,
                               const float* __restrict__ W1l, const float* __restrict__ b1,
                               const float* __restrict__ W1r, float* __restrict__ h1, int nNodes) {
    __shared__ float sW[EMBED * 2 * HIDDEN];   // [k][2*lane] = (Wl, Wr) -> 16 KB
    int tid = threadIdx.x;
    for (int i = tid; i < EMBED * HIDDEN; i += 512) {
        int k = i >> 6, c = i & 63;
        sW[k * 128 + 2 * c]     = W1l[i];
        sW[k * 128 + 2 * c + 1] = W1r[i];
    }
    __syncthreads();

    int wave = tid >> 6, lane = tid & 63;
    float bias = b1[lane];
    int wid = blockIdx.x * 8 + wave, stride = gridDim.x * 8;
    int nPairs = (nNodes + 1) >> 1;
    for (int p = wid; p < nPairs; p += stride) {
        int n0 = 2 * p, n1 = 2 * p + 1;
        bool has1 = (n1 < nNodes);
        // av: lanes 0..31 hold agg1[n][lane], lanes 32..63 hold x[n][lane-32]
        float av0 = (lane < EMBED) ? agg1[(size_t)n0 * EMBED + lane]
                                   : embed[(size_t)node_ids[n0] * EMBED + (lane - EMBED)];
        float av1 = has1 ? ((lane < EMBED) ? agg1[(size_t)n1 * EMBED + lane]
                                           : embed[(size_t)node_ids[n1] * EMBED + (lane - EMBED)])
                         : 0.f;
        float acc0 = bias, acc1 = bias;
        #pragma unroll
        for (int k = 0; k < EMBED; ++k) {
            float2 w = *(const float2*)&sW[k * 128 + 2 * lane];
            acc0 += __shfl(av0, k) * w.x + __shfl(av0, EMBED + k) * w.y;
            acc1 += __shfl(av1, k) * w.x + __shfl(av1, EMBED + k) * w.y;
        }
        h1[(size_t)n0 * HIDDEN + lane] = fmaxf(acc0, 0.f);
        if (has1) h1[(size_t)n1 * HIDDEN + lane] = fmaxf(acc1, 0.f);
    }
}

// layer-2 aggregation: agg2[n][h] = mean_j h1[nbr_j][h]   (no LDS, tiny VGPR, unroll-4)
__launch_bounds__(256)
__global__ void gather2_kernel(const int* __restrict__ nbr, const int* __restrict__ rowptr,
                               const int* __restrict__ deg, const float* __restrict__ h1,
                               float* __restrict__ agg2, int nNodes) {
    int wave = threadIdx.x >> 6, lane = threadIdx.x & 63;
    int wid = blockIdx.x * 4 + wave, stride = gridDim.x * 4;
    for (int n = wid; n < nNodes; n += stride) {
        int dg = deg[n], start = rowptr[n];
        float s0 = 0.f, s1 = 0.f, s2 = 0.f, s3 = 0.f;
        int j = 0;
        for (; j + 3 < dg; j += 4) {
            int n0 = nbr[start + j];
            int n1 = nbr[start + j + 1];
            int n2 = nbr[start + j + 2];
            int n3 = nbr[start + j + 3];
            s0 += h1[(size_t)n0 * HIDDEN + lane];
            s1 += h1[(size_t)n1 * HIDDEN + lane];
            s2 += h1[(size_t)n2 * HIDDEN + lane];
            s3 += h1[(size_t)n3 * HIDDEN + lane];
        }
        for (; j < dg; ++j)
            s0 += h1[(size_t)nbr[start + j] * HIDDEN + lane];
        agg2[(size_t)n * HIDDEN + lane] = ((s0 + s1) + (s2 + s3)) / fmaxf((float)dg, 1.f);
    }
}

// layer-2 update + pool: h2 = relu(agg2@W2l + b2 + x@W2r); pooled[g] += h2
__launch_bounds__(512)
__global__ void update2_kernel(const float* __restrict__ agg2, const float* __restrict__ h1,
                               const float* __restrict__ W2l, const float* __restrict__ b2,
                               const float* __restrict__ W2r, const int* __restrict__ batch,
                               float* __restrict__ pooled, float* __restrict__ gcnt, int nNodes) {
    __shared__ float sW[HIDDEN * 2 * HIDDEN];  // 32 KB
    int tid = threadIdx.x;
    for (int i = tid; i < HIDDEN * HIDDEN; i += 512) {
        int k = i >> 6, c = i & 63;
        sW[k * 128 + 2 * c]     = W2l[i];
        sW[k * 128 + 2 * c + 1] = W2r[i];
    }
    __syncthreads();

    int wave = tid >> 6, lane = tid & 63;
    float bias = b2[lane];
    int wid = blockIdx.x * 8 + wave, stride = gridDim.x * 8;
    int nPairs = (nNodes + 1) >> 1;
    for (int p = wid; p < nPairs; p += stride) {
        int n0 = 2 * p, n1 = 2 * p + 1;
        bool has1 = (n1 < nNodes);
        float ag0 = agg2[(size_t)n0 * HIDDEN + lane];
        float xv0 = h1[(size_t)n0 * HIDDEN + lane];
        float ag1 = has1 ? agg2[(size_t)n1 * HIDDEN + lane] : 0.f;
        float xv1 = has1 ? h1[(size_t)n1 * HIDDEN + lane] : 0.f;
        float acc0 = bias, acc1 = bias;
        #pragma unroll
        for (int k = 0; k < HIDDEN; ++k) {
            float2 w = *(const float2*)&sW[k * 128 + 2 * lane];
            acc0 += __shfl(ag0, k) * w.x + __shfl(xv0, k) * w.y;
            acc1 += __shfl(ag1, k) * w.x + __shfl(xv1, k) * w.y;
        }
        acc0 = fmaxf(acc0, 0.f);
        int g0 = batch[n0];
        atomicAdd(&pooled[(size_t)g0 * HIDDEN + lane], acc0);
        if (has1) {
            acc1 = fmaxf(acc1, 0.f);
            int g1 = batch[n1];
            atomicAdd(&pooled[(size_t)g1 * HIDDEN + lane], acc1);
            if (lane == 0) { atomicAdd(&gcnt[g0], 1.f); atomicAdd(&gcnt[g1], 1.f); }
        } else if (lane == 0) {
            atomicAdd(&gcnt[g0], 1.f);
        }
    }
}

// ============ FALLBACK PATH (round-6 fused kernels, proven) ============

__launch_bounds__(512)
__global__ void layer1_fused(const int* __restrict__ nbr, const int* __restrict__ rowptr,
                             const int* __restrict__ deg, const int* __restrict__ node_ids,
                             const float* __restrict__ embed,
                             const float* __restrict__ W1l, const float* __restrict__ b1,
                             const float* __restrict__ W1r, float* __restrict__ h1, int nNodes) {
    __shared__ float sWl[EMBED * HIDDEN];
    __shared__ float sWr[EMBED * HIDDEN];
    int tid = threadIdx.x;
    for (int i = tid; i < EMBED * HIDDEN; i += 512) { sWl[i] = W1l[i]; sWr[i] = W1r[i]; }
    __syncthreads();
    int wave = tid >> 6, lane = tid & 63;
    int half = lane >> 5, f = lane & 31;
    float bias = b1[lane];
    for (int n = blockIdx.x * 8 + wave; n < nNodes; n += gridDim.x * 8) {
        int dg = deg[n], start = rowptr[n];
        float xv = embed[(size_t)node_ids[n] * EMBED + f];
        float s0 = 0.f, s1 = 0.f;
        int j = half;
        for (; j + 2 < dg; j += 4) {
            int n0 = nbr[start + j];
            int n1 = nbr[start + j + 2];
            s0 += embed[(size_t)node_ids[n0] * EMBED + f];
            s1 += embed[(size_t)node_ids[n1] * EMBED + f];
        }
        for (; j < dg; j += 2)
            s0 += embed[(size_t)node_ids[nbr[start + j]] * EMBED + f];
        float sum = s0 + s1;
        sum += __shfl_xor(sum, 32);
        float aggv = sum / fmaxf((float)dg, 1.f);
        float acc = bias;
        #pragma unroll
        for (int k = 0; k < EMBED; ++k) {
            float a = __shfl(aggv, k);
            float x = __shfl(xv, k);
            acc += a * sWl[k * HIDDEN + lane] + x * sWr[k * HIDDEN + lane];
        }
        h1[(size_t)n * HIDDEN + lane] = fmaxf(acc, 0.f);
    }
}

__launch_bounds__(512)
__global__ void layer2_fused(const int* __restrict__ nbr, const int* __restrict__ rowptr,
                             const int* __restrict__ deg, const float* __restrict__ h1,
                             const float* __restrict__ W2l, const float* __restrict__ b2,
                             const float* __restrict__ W2r, const int* __restrict__ batch,
                             float* __restrict__ pooled, float* __restrict__ gcnt, int nNodes) {
    __shared__ float sWl[HIDDEN * HIDDEN];
    __shared__ float sWr[HIDDEN * HIDDEN];
    int tid = threadIdx.x;
    for (int i = tid; i < HIDDEN * HIDDEN; i += 512) { sWl[i] = W2l[i]; sWr[i] = W2r[i]; }
    __syncthreads();
    int wave = tid >> 6, lane = tid & 63;
    float bias = b2[lane];
    for (int n = blockIdx.x * 8 + wave; n < nNodes; n += gridDim.x * 8) {
        int dg = deg[n], start = rowptr[n];
        int g = batch[n];
        float xv = h1[(size_t)n * HIDDEN + lane];
        float s0 = 0.f, s1 = 0.f, s2 = 0.f, s3 = 0.f;
        int j = 0;
        for (; j + 3 < dg; j += 4) {
            int n0 = nbr[start + j];
            int n1 = nbr[start + j + 1];
            int n2 = nbr[start + j + 2];
            int n3 = nbr[start + j + 3];
            s0 += h1[(size_t)n0 * HIDDEN + lane];
            s1 += h1[(size_t)n1 * HIDDEN + lane];
            s2 += h1[(size_t)n2 * HIDDEN + lane];
            s3 += h1[(size_t)n3 * HIDDEN + lane];
        }
        for (; j < dg; ++j)
            s0 += h1[(size_t)nbr[start + j] * HIDDEN + lane];
        float aggv = ((s0 + s1) + (s2 + s3)) / fmaxf((float)dg, 1.f);
        float acc = bias;
        #pragma unroll
        for (int k = 0; k < HIDDEN; ++k) {
            float a = __shfl(aggv, k);
            float x = __shfl(xv, k);
            acc += a * sWl[k * HIDDEN + lane] + x * sWr[k * HIDDEN + lane];
        }
        acc = fmaxf(acc, 0.f);
        atomicAdd(&pooled[(size_t)g * HIDDEN + lane], acc);
        if (lane == 0) atomicAdd(&gcnt[g], 1.f);
    }
}

// ============ classifier ============
__global__ void out_kernel(const float* __restrict__ pooled, const float* __restrict__ gcnt,
                           const float* __restrict__ Wout, const float* __restrict__ bout,
                           float* __restrict__ out, int nGraphs) {
    int i = blockIdx.x * blockDim.x + threadIdx.x;
    if (i >= nGraphs * NCLS) return;
    int g = i / NCLS;
    int c = i % NCLS;
    float inv = 1.0f / fmaxf(gcnt[g], 1.0f);
    float acc = bout[c];
    #pragma unroll
    for (int k = 0; k < HIDDEN; ++k)
        acc += pooled[(size_t)g * HIDDEN + k] * inv * Wout[k * NCLS + c];
    out[i] = acc;
}

extern "C" void kernel_launch(void* const* d_in, const int* in_sizes, int n_in,
                              void* d_out, int out_size, void* d_ws, size_t ws_size,
                              hipStream_t stream) {
    const int*   node_ids = (const int*)d_in[0];
    const int*   src      = (const int*)d_in[1];
    const int*   dst      = (const int*)d_in[2];
    const int*   batch    = (const int*)d_in[3];
    const float* embed    = (const float*)d_in[4];
    const float* W1l      = (const float*)d_in[5];
    const float* b1       = (const float*)d_in[6];
    const float* W1r      = (const float*)d_in[7];
    const float* W2l      = (const float*)d_in[8];
    const float* b2       = (const float*)d_in[9];
    const float* W2r      = (const float*)d_in[10];
    const float* Wout     = (const float*)d_in[11];
    const float* bout     = (const float*)d_in[12];

    const int N = in_sizes[0];          // 100000
    const int E = in_sizes[1];          // 1200000
    const int G = out_size / NCLS;      // 1024
    const int NB = (N + 255) / 256;

    // workspace: deg|rowptr|cursor|blockSums(pad)|nbr(pad) (ints),
    //            h1[N*64]|pooled[G*64]|gcnt(pad 64) (floats), then agg[N*64] if it fits
    int* deg       = (int*)d_ws;
    int* rowptr    = deg + N;
    int* cursor    = rowptr + N;
    int* blockSums = cursor + N;
    int* nbr       = blockSums + ((NB + 63) & ~63);
    float* h1      = (float*)(nbr + ((E + 63) & ~63));
    float* pooled  = h1 + (size_t)N * HIDDEN;
    float* gcnt    = pooled + (size_t)G * HIDDEN;
    float* agg     = gcnt + 64;                       // agg1 uses N*EMBED, agg2 uses N*HIDDEN

    size_t need_split = ((char*)(agg + (size_t)N * HIDDEN)) - (char*)d_ws;
    const bool use_split = (ws_size >= need_split);   // constant across calls -> graph-safe

    float* out = (float*)d_out;

    // ---- CSR build ----
    hipMemsetAsync(deg, 0, (size_t)N * sizeof(int), stream);
    hipMemsetAsync(cursor, 0, (size_t)N * sizeof(int), stream);
    deg_kernel<<<(E + 255) / 256, 256, 0, stream>>>(dst, deg, E);
    block_sum_kernel<<<NB, 256, 0, stream>>>(deg, blockSums, N);
    scan_sums_kernel<<<1, 1, 0, stream>>>(blockSums, NB);
    scan_local_kernel<<<NB, 256, 0, stream>>>(deg, blockSums, rowptr, N);
    fill_kernel<<<(E + 255) / 256, 256, 0, stream>>>(src, dst, rowptr, cursor, nbr, E);

    hipMemsetAsync(pooled, 0, (size_t)G * HIDDEN * sizeof(float), stream);
    hipMemsetAsync(gcnt, 0, (size_t)G * sizeof(float), stream);

    if (use_split) {
        gather1_kernel<<<2048, 256, 0, stream>>>(nbr, rowptr, deg, node_ids, embed, agg, N);
        update1_kernel<<<1024, 512, 0, stream>>>(agg, node_ids, embed, W1l, b1, W1r, h1, N);
        gather2_kernel<<<2048, 256, 0, stream>>>(nbr, rowptr, deg, h1, agg, N);
        update2_kernel<<<1024, 512, 0, stream>>>(agg, h1, W2l, b2, W2r, batch, pooled, gcnt, N);
    } else {
        layer1_fused<<<1024, 512, 0, stream>>>(nbr, rowptr, deg, node_ids, embed,
                                               W1l, b1, W1r, h1, N);
        layer2_fused<<<1024, 512, 0, stream>>>(nbr, rowptr, deg, h1, W2l, b2, W2r,
                                               batch, pooled, gcnt, N);
    }

    // ---- classifier ----
    out_kernel<<<(G * NCLS + 255) / 256, 256, 0, stream>>>(pooled, gcnt, Wout, bout, out, G);
}